// Round 2
// baseline (288.148 us; speedup 1.0000x reference)
//
#include <hip/hip_runtime.h>
#include <math.h>

#define S_SPOTS 2048
#define B_BINS 3000
#define E_EDGES 12288
#define SB_TOTAL (S_SPOTS * B_BINS)   /* 6,144,000 */
#define SB4 (SB_TOTAL / 4)            /* 1,536,000 */

// ws layout:
//   [0, SB_TOTAL)             : uint8 state code per (spot,bin)
//   [SB_TOTAL, +4)            : uint32 mismatch counter (zeroed by prep)
//   [SB_TOTAL+16, +64)        : double params: recip_std[0..2], cc[0..2]
//                               cc_k = -log(std_k) - HALF_LOG_2PI

__global__ void prep_kernel(const float* __restrict__ log_stds,
                            double* __restrict__ params,
                            unsigned int* __restrict__ counter) {
    if (threadIdx.x == 0 && blockIdx.x == 0) {
        *counter = 0u;
        const double CHALF = 0.9189385332046727;  // exact f64 of ref const
        for (int k = 0; k < 3; ++k) {
            // numpy-f64 sequence: std = exp(ls) + 1e-6 ; c = log(std)
            double sd = exp((double)log_stds[k]) + 1e-6;
            params[k]     = 1.0 / sd;        // recip-mul: ~1ulp vs true div,
            params[3 + k] = -log(sd) - CHALF;// far below argmax tie window
        }
    }
}

__global__ __launch_bounds__(256) void map_kernel(
        const float4* __restrict__ x4,
        const float4* __restrict__ g4,
        const float* __restrict__ state_means,
        const double* __restrict__ params,
        float4* __restrict__ out4,
        uchar4* __restrict__ st4) {
    int i = blockIdx.x * 256 + threadIdx.x;
    if (i >= SB4) return;
    float m0f = state_means[0];
    float m2f = state_means[1];
    double m0 = (double)m0f, m2 = (double)m2f;       // exact promotions
    double r0 = params[0], r1 = params[1], r2 = params[2];
    double cc0 = params[3], cc1 = params[4], cc2 = params[5];

    float4 xv = x4[i];
    float4 ga = g4[3 * i + 0];
    float4 gb = g4[3 * i + 1];
    float4 gc = g4[3 * i + 2];
    float xs[4]  = {xv.x, xv.y, xv.z, xv.w};
    float gs[12] = {ga.x, ga.y, ga.z, ga.w, gb.x, gb.y, gb.z, gb.w,
                    gc.x, gc.y, gc.z, gc.w};
    float os[4];
    unsigned int codes[4];
#pragma unroll
    for (int j = 0; j < 4; ++j) {
        double x = (double)xs[j];                    // exact f32->f64
        // f64 logits, <=2ulp from numpy-f64 ref values; argmax-safe.
        double z0 = (x - m0) * r0;
        double z1 = x * r1;
        double z2 = (x - m2) * r2;
        double l0 = fma(-0.5 * z0, z0, cc0) + (double)gs[3 * j + 0];
        double l1 = fma(-0.5 * z1, z1, cc1) + (double)gs[3 * j + 1];
        double l2 = fma(-0.5 * z2, z2, cc2) + (double)gs[3 * j + 2];
        // /TAU + softmax are monotone in f64; np.argmax = first-max-wins
        int k = 0; double best = l0;
        if (l1 > best) { best = l1; k = 1; }
        if (l2 > best) { best = l2; k = 2; }
        os[j]    = (k == 0) ? m0f : ((k == 1) ? 0.0f : m2f);
        codes[j] = (unsigned)k;
    }
    out4[i] = make_float4(os[0], os[1], os[2], os[3]);
    st4[i]  = make_uchar4((unsigned char)codes[0], (unsigned char)codes[1],
                          (unsigned char)codes[2], (unsigned char)codes[3]);
}

__global__ __launch_bounds__(256) void edge_kernel(
        const int* __restrict__ edge_index,
        const unsigned char* __restrict__ st,
        unsigned int* __restrict__ counter) {
    int e = blockIdx.x;
    int r = edge_index[e];
    int c = edge_index[E_EDGES + e];
    // rows are 3000 B each; 3000 % 8 == 0 -> uint2 loads stay aligned
    const uint2* pr = (const uint2*)(st + (size_t)r * B_BINS);
    const uint2* pc = (const uint2*)(st + (size_t)c * B_BINS);
    unsigned int cnt = 0;
    for (int j = threadIdx.x; j < B_BINS / 8; j += 256) {  // 375 uint2/row
        uint2 a = pr[j];
        uint2 b = pc[j];
        unsigned v0 = a.x ^ b.x;
        unsigned v1 = a.y ^ b.y;
        // nonzero-byte detect -> one bit per mismatched (edge,bin) pair
        unsigned n0 = (((v0 & 0x7F7F7F7Fu) + 0x7F7F7F7Fu) | v0) & 0x80808080u;
        unsigned n1 = (((v1 & 0x7F7F7F7Fu) + 0x7F7F7F7Fu) | v1) & 0x80808080u;
        cnt += (unsigned)__popc(n0) + (unsigned)__popc(n1);
    }
    for (int off = 32; off > 0; off >>= 1)
        cnt += __shfl_down(cnt, off, 64);
    __shared__ unsigned int wsum[4];
    int lane = threadIdx.x & 63;
    int wid  = threadIdx.x >> 6;
    if (lane == 0) wsum[wid] = cnt;
    __syncthreads();
    if (threadIdx.x == 0)
        atomicAdd(counter, wsum[0] + wsum[1] + wsum[2] + wsum[3]);
}

__global__ void fin_kernel(const unsigned int* __restrict__ counter,
                           float* __restrict__ out) {
    if (threadIdx.x == 0 && blockIdx.x == 0) {
        // each mismatching (edge,bin) contributes exactly 2.0 to sum(diff^2)
        // match ref f64 op order: mean = sum/N ; loss = 0.1 * mean
        double sum  = 2.0 * (double)(*counter);          // exact (< 2^53)
        double mean = sum / ((double)E_EDGES * (double)B_BINS * 3.0);
        out[SB_TOTAL] = (float)(0.1 * mean);             // LAMBDA_SMOOTH
    }
}

extern "C" void kernel_launch(void* const* d_in, const int* in_sizes, int n_in,
                              void* d_out, int out_size, void* d_ws, size_t ws_size,
                              hipStream_t stream) {
    const float* x           = (const float*)d_in[0];
    /* d_in[1] = bin_idx — arange(B) identity gather, no-op */
    const int*   edge_index  = (const int*)d_in[2];
    const float* gumbel      = (const float*)d_in[3];
    const float* state_means = (const float*)d_in[4];
    const float* log_stds    = (const float*)d_in[5];
    float* out = (float*)d_out;

    unsigned char* st      = (unsigned char*)d_ws;
    unsigned int*  counter = (unsigned int*)((char*)d_ws + SB_TOTAL);
    double*        params  = (double*)((char*)d_ws + SB_TOTAL + 16);

    prep_kernel<<<1, 64, 0, stream>>>(log_stds, params, counter);
    map_kernel<<<SB4 / 256, 256, 0, stream>>>(
        (const float4*)x, (const float4*)gumbel, state_means, params,
        (float4*)d_out, (uchar4*)st);
    edge_kernel<<<E_EDGES, 256, 0, stream>>>(edge_index, st, counter);
    fin_kernel<<<1, 64, 0, stream>>>(counter, out);
}

// Round 3
// 171.637 us; speedup vs baseline: 1.6788x; 1.6788x over previous
//
#include <hip/hip_runtime.h>
#include <math.h>

#define S_SPOTS 2048
#define B_BINS 3000
#define E_EDGES 12288
#define SB_TOTAL (S_SPOTS * B_BINS)   /* 6,144,000 */
#define SB4 (SB_TOTAL / 4)            /* 1,536,000 map threads */
#define ROW_BYTES 768                 /* 750 data + 18 zero pad */
#define ROW_DW 192
#define ST_BYTES (S_SPOTS * ROW_BYTES) /* 1,572,864 */

// ws layout: [0, ST_BYTES) packed 2-bit states; [ST_BYTES, +4) mismatch
// counter; [ST_BYTES+4, +8) done counter. All zeroed by one memsetAsync.

__global__ __launch_bounds__(256) void map_kernel(
        const float4* __restrict__ x4,
        const float4* __restrict__ g4,
        const float* __restrict__ state_means,
        const float* __restrict__ log_stds,
        float4* __restrict__ out4,
        unsigned char* __restrict__ st) {
    __shared__ float4 lg[768];     // 12 KB gumbel tile
    __shared__ double sp[6];
    int tid = threadIdx.x;
    int blk = blockIdx.x;

    if (tid == 0) {
        const double CHALF = 0.9189385332046727;
        for (int k = 0; k < 3; ++k) {
            // numpy-f64 sequence: std = exp(ls)+1e-6 ; recip-mul ~1ulp
            double sd = exp((double)log_stds[k]) + 1e-6;
            sp[k]     = 1.0 / sd;
            sp[3 + k] = -log(sd) - CHALF;
        }
    }
    // coalesced staging: block's 3072 gumbel floats = 768 float4
    const float4* gg = g4 + (size_t)blk * 768;
    float4 t0 = gg[tid];
    float4 t1 = gg[tid + 256];
    float4 t2 = gg[tid + 512];
    int gi = blk * 256 + tid;
    float4 xv = x4[gi];
    float m0f = state_means[0];
    float m2f = state_means[1];
    lg[tid] = t0; lg[tid + 256] = t1; lg[tid + 512] = t2;
    __syncthreads();

    double r0 = sp[0], r1 = sp[1], r2 = sp[2];
    double cc0 = sp[3], cc1 = sp[4], cc2 = sp[5];
    double m0 = (double)m0f, m2 = (double)m2f;

    // per-thread 48B LDS read (16B-aligned); bank-balanced at the b128 floor
    const float4* myg = (const float4*)((const char*)lg + 48 * tid);
    float4 ga = myg[0], gb = myg[1], gc = myg[2];
    float xs[4]  = {xv.x, xv.y, xv.z, xv.w};
    float gs[12] = {ga.x, ga.y, ga.z, ga.w, gb.x, gb.y, gb.z, gb.w,
                    gc.x, gc.y, gc.z, gc.w};
    float os[4];
    unsigned pk = 0;
#pragma unroll
    for (int j = 0; j < 4; ++j) {
        double x = (double)xs[j];
        // f64 logits, <=2ulp vs numpy-f64 ref; argmax-safe
        double z0 = (x - m0) * r0;
        double z1 = x * r1;
        double z2 = (x - m2) * r2;
        double l0 = fma(-0.5 * z0, z0, cc0) + (double)gs[3 * j + 0];
        double l1 = fma(-0.5 * z1, z1, cc1) + (double)gs[3 * j + 1];
        double l2 = fma(-0.5 * z2, z2, cc2) + (double)gs[3 * j + 2];
        int k = 0; double best = l0;
        if (l1 > best) { best = l1; k = 1; }
        if (l2 > best) { best = l2; k = 2; }
        os[j] = (k == 0) ? m0f : ((k == 1) ? 0.0f : m2f);
        pk |= (unsigned)k << (2 * j);
    }
    out4[gi] = make_float4(os[0], os[1], os[2], os[3]);
    // packed 2-bit store: 1 byte per thread, wave-coalesced
    unsigned sb0  = 4u * (unsigned)gi;
    unsigned row  = sb0 / 3000u;          // compile-time-const divisor
    unsigned colb = (sb0 % 3000u) >> 2;
    st[row * ROW_BYTES + colb] = (unsigned char)pk;
}

__global__ __launch_bounds__(256) void edge_kernel(
        const int* __restrict__ edge_index,
        const unsigned int* __restrict__ st,   // dword view of packed table
        unsigned int* __restrict__ counter,
        unsigned int* __restrict__ done,
        float* __restrict__ out) {
    int lane = threadIdx.x & 63;
    int wid  = threadIdx.x >> 6;
    int gw   = blockIdx.x * 4 + wid;      // 4096 waves x 3 edges = 12288
    unsigned cnt = 0;
#pragma unroll
    for (int t = 0; t < 3; ++t) {
        int e = gw * 3 + t;
        int r = edge_index[e];
        int c = edge_index[E_EDGES + e];
        const unsigned* pr = st + r * ROW_DW;
        const unsigned* pc = st + c * ROW_DW;
        // 3 coalesced 256B transactions per row; table is L2-resident
        unsigned a0 = pr[lane], a1 = pr[lane + 64], a2 = pr[lane + 128];
        unsigned b0 = pc[lane], b1 = pc[lane + 64], b2 = pc[lane + 128];
        unsigned v0 = a0 ^ b0, v1 = a1 ^ b1, v2 = a2 ^ b2;
        // nonzero 2-bit group => states differ at that bin
        cnt += (unsigned)__popc((v0 | (v0 >> 1)) & 0x55555555u);
        cnt += (unsigned)__popc((v1 | (v1 >> 1)) & 0x55555555u);
        cnt += (unsigned)__popc((v2 | (v2 >> 1)) & 0x55555555u);
    }
    for (int off = 32; off; off >>= 1)
        cnt += __shfl_down(cnt, off, 64);
    __shared__ unsigned wsum[4];
    if (lane == 0) wsum[wid] = cnt;
    __syncthreads();
    if (threadIdx.x == 0) {
        unsigned bs = wsum[0] + wsum[1] + wsum[2] + wsum[3];
        atomicAdd(counter, bs);
        __threadfence();
        unsigned old = atomicAdd(done, 1u);
        if (old == gridDim.x - 1) {           // last block finalizes loss
            __threadfence();
            unsigned total = atomicAdd(counter, 0u);   // atomic read
            // each mismatching (edge,bin) contributes exactly 2.0
            double sum  = 2.0 * (double)total;
            double mean = sum / ((double)E_EDGES * (double)B_BINS * 3.0);
            out[SB_TOTAL] = (float)(0.1 * mean);       // LAMBDA_SMOOTH
        }
    }
}

extern "C" void kernel_launch(void* const* d_in, const int* in_sizes, int n_in,
                              void* d_out, int out_size, void* d_ws, size_t ws_size,
                              hipStream_t stream) {
    const float* x           = (const float*)d_in[0];
    /* d_in[1] = bin_idx — arange(B) identity gather, no-op */
    const int*   edge_index  = (const int*)d_in[2];
    const float* gumbel      = (const float*)d_in[3];
    const float* state_means = (const float*)d_in[4];
    const float* log_stds    = (const float*)d_in[5];
    float* out = (float*)d_out;

    unsigned char* st      = (unsigned char*)d_ws;
    unsigned int*  counter = (unsigned int*)((char*)d_ws + ST_BYTES);
    unsigned int*  done    = counter + 1;

    // zero pad bytes + both counters (ws is re-poisoned 0xAA every call)
    hipMemsetAsync(d_ws, 0, ST_BYTES + 8, stream);

    map_kernel<<<SB4 / 256, 256, 0, stream>>>(
        (const float4*)x, (const float4*)gumbel, state_means, log_stds,
        (float4*)d_out, st);
    edge_kernel<<<E_EDGES / 12, 256, 0, stream>>>(
        edge_index, (const unsigned int*)st, counter, done, out);
}